// Round 1
// baseline (1213.664 us; speedup 1.0000x reference)
//
#include <hip/hip_runtime.h>
#include <math.h>

// BertFlashSelfAttention (varlen, H=16, D=64) — fp32 baseline.
// Phase 1: QKV = hidden @ W^T + bias  -> Q,K,V in d_ws   (vector fp32 SGEMM)
// Phase 2: per-(seq,head,qtile) flash attention -> d_out (fp32)

#define HD 64  // head dim

// ---------------------------------------------------------------------------
// QKV GEMM: C[m][n] = sum_k A[m][k] * W[n][k] + bias[n]
// BM=BN=128, BK=16, 256 threads, 8x8 microtile (split 4+4).
// ---------------------------------------------------------------------------
__global__ __launch_bounds__(256)
void qkv_gemm_kernel(const float* __restrict__ A, const float* __restrict__ W,
                     const float* __restrict__ bias,
                     float* __restrict__ Qo, float* __restrict__ Ko, float* __restrict__ Vo,
                     int M, int Kd, int dim)
{
    const int bm = blockIdx.x;
    const int bn = blockIdx.y;
    const int t  = threadIdx.x;
    const int tx = t & 15;        // col group
    const int ty = t >> 4;        // row group

    __shared__ float As[16][132]; // k-major, stride 132 (16B aligned, conflict-free-ish)
    __shared__ float Bs[16][132];

    float acc[8][8];
#pragma unroll
    for (int i = 0; i < 8; ++i)
#pragma unroll
        for (int j = 0; j < 8; ++j) acc[i][j] = 0.f;

    const int m0 = bm * 128, n0 = bn * 128;

    for (int k0 = 0; k0 < Kd; k0 += 16) {
#pragma unroll
        for (int l = 0; l < 2; ++l) {
            int id  = t + l * 256;          // float4 id 0..511
            int row = id >> 2;              // 0..127
            int kq  = (id & 3) * 4;         // k offset 0,4,8,12
            // A tile
            float4 av = make_float4(0.f, 0.f, 0.f, 0.f);
            int gm = m0 + row;
            if (gm < M) av = *(const float4*)(A + (size_t)gm * Kd + k0 + kq);
            As[kq + 0][row] = av.x; As[kq + 1][row] = av.y;
            As[kq + 2][row] = av.z; As[kq + 3][row] = av.w;
            // W tile (row n0+row of W, contiguous in k)
            float4 bv = *(const float4*)(W + (size_t)(n0 + row) * Kd + k0 + kq);
            Bs[kq + 0][row] = bv.x; Bs[kq + 1][row] = bv.y;
            Bs[kq + 2][row] = bv.z; Bs[kq + 3][row] = bv.w;
        }
        __syncthreads();

#pragma unroll
        for (int k = 0; k < 16; ++k) {
            float a[8], b[8];
            *(float4*)&a[0] = *(const float4*)&As[k][ty * 4];
            *(float4*)&a[4] = *(const float4*)&As[k][64 + ty * 4];
            *(float4*)&b[0] = *(const float4*)&Bs[k][tx * 4];
            *(float4*)&b[4] = *(const float4*)&Bs[k][64 + tx * 4];
#pragma unroll
            for (int i = 0; i < 8; ++i)
#pragma unroll
                for (int j = 0; j < 8; ++j)
                    acc[i][j] = fmaf(a[i], b[j], acc[i][j]);
        }
        __syncthreads();
    }

    // epilogue: add bias, scatter to Q/K/V (each (nnz, dim) with dim=H*HD)
#pragma unroll
    for (int i = 0; i < 8; ++i) {
        int rloc = (i < 4) ? (ty * 4 + i) : (64 + ty * 4 + i - 4);
        int gm = m0 + rloc;
        if (gm >= M) continue;
#pragma unroll
        for (int jh = 0; jh < 2; ++jh) {
            int cloc = jh * 64 + tx * 4;
            int n = n0 + cloc;
            float4 c;
            c.x = acc[i][jh * 4 + 0] + bias[n + 0];
            c.y = acc[i][jh * 4 + 1] + bias[n + 1];
            c.z = acc[i][jh * 4 + 2] + bias[n + 2];
            c.w = acc[i][jh * 4 + 3] + bias[n + 3];
            int which = n / dim;          // 0=Q 1=K 2=V  (BN=128 never straddles)
            int off   = n - which * dim;
            float* dst = (which == 0) ? Qo : (which == 1) ? Ko : Vo;
            *(float4*)(dst + (size_t)gm * dim + off) = c;
        }
    }
}

// ---------------------------------------------------------------------------
// Flash attention: one block per (seq b, head h, q-tile of 64 rows).
// K staged transposed [d][c]; P reuses the K buffer; online softmax.
// ---------------------------------------------------------------------------
__global__ __launch_bounds__(256)
void attn_kernel(const float* __restrict__ Q, const float* __restrict__ K,
                 const float* __restrict__ V, const int* __restrict__ cu,
                 float* __restrict__ out, int dim, int H)
{
    const int bh = blockIdx.x;
    const int b  = bh / H;
    const int h  = bh - b * H;
    const int qt = blockIdx.y;

    const int s0 = cu[b], s1 = cu[b + 1];
    const int L  = s1 - s0;
    if (qt * 64 >= L) return;

    const int t  = threadIdx.x;
    const int tx = t & 15;   // c0 = tx*4
    const int ty = t >> 4;   // r0 = ty*4

    __shared__ float Qts[64][68];   // [d][r]
    __shared__ float KPs[64][68];   // phase A: Kt [d][c]; phase B: P [r][k]
    __shared__ float Vs [64][68];   // [k][d]

    // ---- stage Q transposed ----
    {
        int r = t & 63, dgrp = t >> 6;         // dgrp 0..3 -> d = dgrp*16..+15
        int qrow = qt * 64 + r;
        const float* src = Q + (size_t)(s0 + qrow) * dim + h * HD + dgrp * 16;
#pragma unroll
        for (int q4 = 0; q4 < 4; ++q4) {
            float4 v = make_float4(0.f, 0.f, 0.f, 0.f);
            if (qrow < L) v = *(const float4*)(src + q4 * 4);
            int d = dgrp * 16 + q4 * 4;
            Qts[d + 0][r] = v.x; Qts[d + 1][r] = v.y;
            Qts[d + 2][r] = v.z; Qts[d + 3][r] = v.w;
        }
    }

    float o[4][4];
    float m_run[4], l_run[4];
#pragma unroll
    for (int i = 0; i < 4; ++i) {
        m_run[i] = -3.0e38f; l_run[i] = 0.f;
#pragma unroll
        for (int j = 0; j < 4; ++j) o[i][j] = 0.f;
    }

    const float scale = rsqrtf((float)HD);
    const int nkt = (L + 63) >> 6;

    for (int kt = 0; kt < nkt; ++kt) {
        __syncthreads();  // previous PV done; Q stage visible on first iter

        // ---- stage K (transposed) and V ----
        {
            int c = t & 63, dgrp = t >> 6;
            int krow = kt * 64 + c;
            const float* srcK = K + (size_t)(s0 + krow) * dim + h * HD + dgrp * 16;
#pragma unroll
            for (int q4 = 0; q4 < 4; ++q4) {
                float4 v = make_float4(0.f, 0.f, 0.f, 0.f);
                if (krow < L) v = *(const float4*)(srcK + q4 * 4);
                int d = dgrp * 16 + q4 * 4;
                KPs[d + 0][c] = v.x; KPs[d + 1][c] = v.y;
                KPs[d + 2][c] = v.z; KPs[d + 3][c] = v.w;
            }
            int kv = t >> 2, dq = (t & 3) * 16;   // V natural: 1 key row, 16 d
            int vrow = kt * 64 + kv;
            const float* srcV = V + (size_t)(s0 + vrow) * dim + h * HD + dq;
#pragma unroll
            for (int q4 = 0; q4 < 4; ++q4) {
                float4 v = make_float4(0.f, 0.f, 0.f, 0.f);
                if (vrow < L) v = *(const float4*)(srcV + q4 * 4);
                *(float4*)&Vs[kv][dq + q4 * 4] = v;
            }
        }
        __syncthreads();

        // ---- S = scale * Q K^T  (each thread 4x4) ----
        float s[4][4];
#pragma unroll
        for (int i = 0; i < 4; ++i)
#pragma unroll
            for (int j = 0; j < 4; ++j) s[i][j] = 0.f;

        for (int d = 0; d < 64; ++d) {
            float4 qv = *(const float4*)&Qts[d][ty * 4];
            float4 kv = *(const float4*)&KPs[d][tx * 4];
            float qa[4] = {qv.x, qv.y, qv.z, qv.w};
            float ka[4] = {kv.x, kv.y, kv.z, kv.w};
#pragma unroll
            for (int i = 0; i < 4; ++i)
#pragma unroll
                for (int j = 0; j < 4; ++j)
                    s[i][j] = fmaf(qa[i], ka[j], s[i][j]);
        }
#pragma unroll
        for (int i = 0; i < 4; ++i)
#pragma unroll
            for (int j = 0; j < 4; ++j) {
                int kg = kt * 64 + tx * 4 + j;
                s[i][j] = (kg < L) ? s[i][j] * scale : -1.0e30f;
            }

        // ---- online softmax (row reduce across the 16 tx lanes) ----
        float fac[4];
#pragma unroll
        for (int i = 0; i < 4; ++i) {
            float mx = fmaxf(fmaxf(s[i][0], s[i][1]), fmaxf(s[i][2], s[i][3]));
            mx = fmaxf(mx, __shfl_xor(mx, 1));
            mx = fmaxf(mx, __shfl_xor(mx, 2));
            mx = fmaxf(mx, __shfl_xor(mx, 4));
            mx = fmaxf(mx, __shfl_xor(mx, 8));
            float mnew = fmaxf(m_run[i], mx);
            fac[i] = __expf(m_run[i] - mnew);
            m_run[i] = mnew;
            float ls = 0.f;
#pragma unroll
            for (int j = 0; j < 4; ++j) {
                s[i][j] = __expf(s[i][j] - mnew);
                ls += s[i][j];
            }
            ls += __shfl_xor(ls, 1);
            ls += __shfl_xor(ls, 2);
            ls += __shfl_xor(ls, 4);
            ls += __shfl_xor(ls, 8);
            l_run[i] = l_run[i] * fac[i] + ls;
#pragma unroll
            for (int j = 0; j < 4; ++j) o[i][j] *= fac[i];
        }

        __syncthreads();  // all Kt reads done; safe to overwrite with P

        // ---- write P into KPs as [r][k] ----
#pragma unroll
        for (int i = 0; i < 4; ++i)
            *(float4*)&KPs[ty * 4 + i][tx * 4] = *(float4*)&s[i][0];

        __syncthreads();

        // ---- O += P @ V ----
        for (int k = 0; k < 64; ++k) {
            float4 vv = *(const float4*)&Vs[k][tx * 4];
            float va[4] = {vv.x, vv.y, vv.z, vv.w};
            float pr[4];
#pragma unroll
            for (int i = 0; i < 4; ++i) pr[i] = KPs[ty * 4 + i][k];
#pragma unroll
            for (int i = 0; i < 4; ++i)
#pragma unroll
                for (int j = 0; j < 4; ++j)
                    o[i][j] = fmaf(pr[i], va[j], o[i][j]);
        }
    }

    // ---- normalize + store ----
#pragma unroll
    for (int i = 0; i < 4; ++i) {
        int qrow = qt * 64 + ty * 4 + i;
        if (qrow >= L) continue;
        float inv = 1.0f / l_run[i];
        float4 c;
        c.x = o[i][0] * inv; c.y = o[i][1] * inv;
        c.z = o[i][2] * inv; c.w = o[i][3] * inv;
        *(float4*)(out + (size_t)(s0 + qrow) * dim + h * HD + tx * 4) = c;
    }
}

// ---------------------------------------------------------------------------
extern "C" void kernel_launch(void* const* d_in, const int* in_sizes, int n_in,
                              void* d_out, int out_size, void* d_ws, size_t ws_size,
                              hipStream_t stream)
{
    const float* hs   = (const float*)d_in[0];
    const float* W    = (const float*)d_in[1];
    const float* bias = (const float*)d_in[2];
    const int*   cu   = (const int*)d_in[3];
    // d_in[4] = max_seqlen (device scalar, unused — grid bounded by nnz)

    const int dim3x = in_sizes[2];        // 3*dim
    const int dim   = dim3x / 3;          // 1024
    const int nnz   = in_sizes[0] / dim;  // 8704
    const int B     = in_sizes[3] - 1;    // 16
    const int H     = dim / HD;           // 16

    float* Qw = (float*)d_ws;
    float* Kw = Qw + (size_t)nnz * dim;
    float* Vw = Kw + (size_t)nnz * dim;

    dim3 g1((nnz + 127) / 128, dim3x / 128);
    qkv_gemm_kernel<<<g1, 256, 0, stream>>>(hs, W, bias, Qw, Kw, Vw, nnz, dim, dim);

    dim3 g2(B * H, (nnz + 63) / 64);      // q-tile grid bounded by nnz/64; empty tiles exit
    attn_kernel<<<g2, 256, 0, stream>>>(Qw, Kw, Vw, cu, (float*)d_out, dim, H);
}

// Round 3
// 583.797 us; speedup vs baseline: 2.0789x; 2.0789x over previous
//
#include <hip/hip_runtime.h>
#include <math.h>

// BertFlashSelfAttention (varlen, H=16, D=64)
// Phase 0: convert hidden (fp32) and Wqkv (fp32) -> f16 in ws
// Phase 1: QKV GEMM via mfma_f32_16x16x32_f16 (m97-style 128x128 tile),
//          epilogue adds bias, writes Q,K,V as f16 to ws
// Phase 2: flash attention (fp32 vector math, f16 staging loads) -> d_out fp32

#define HD 64

typedef _Float16 half8 __attribute__((ext_vector_type(8)));
typedef _Float16 half4v __attribute__((ext_vector_type(4)));
typedef float f32x4 __attribute__((ext_vector_type(4)));

#define GLP(p) ((__attribute__((address_space(1))) void*)(p))
#define LDSP(p) ((__attribute__((address_space(3))) void*)(p))

// ---------------------------------------------------------------------------
// fp32 -> f16 conversion (grid-stride, float4 in / half4 out)
// ---------------------------------------------------------------------------
__global__ __launch_bounds__(256)
void cvt_kernel(const float* __restrict__ A, const float* __restrict__ W,
                _Float16* __restrict__ Ah, _Float16* __restrict__ Wh,
                int nA4, int nW4)
{
    int total = nA4 + nW4;
    for (int i = blockIdx.x * blockDim.x + threadIdx.x; i < total;
         i += gridDim.x * blockDim.x) {
        const float* src; _Float16* dst; int j;
        if (i < nA4) { src = A; dst = Ah; j = i; }
        else         { src = W; dst = Wh; j = i - nA4; }
        float4 v = *(const float4*)(src + (size_t)j * 4);
        half4v h;
        h.x = (_Float16)v.x; h.y = (_Float16)v.y;
        h.z = (_Float16)v.z; h.w = (_Float16)v.w;
        *(half4v*)(dst + (size_t)j * 4) = h;
    }
}

// ---------------------------------------------------------------------------
// QKV GEMM: C[m][n] = sum_k A[m][k]*W[n][k] + bias[n], f16 inputs, MFMA.
// BM=BN=128, BK=32, 256 threads (4 waves, 2x2), wave tile 64x64.
// M=8704, N=3072, K=1024 all exactly divisible -> no bounds checks.
// ---------------------------------------------------------------------------
__global__ __launch_bounds__(256)
void qkv_gemm_kernel(const _Float16* __restrict__ Ah, const _Float16* __restrict__ Wh,
                     const float* __restrict__ bias,
                     _Float16* __restrict__ Qo, _Float16* __restrict__ Ko,
                     _Float16* __restrict__ Vo,
                     int Kd, int dim)
{
    const int bm = blockIdx.x, bn = blockIdx.y;
    const int t = threadIdx.x;
    const int wid = t >> 6, lane = t & 63;
    const int wr = wid >> 1, wc = wid & 1;
    const int fr = lane & 15, fq = lane >> 4;

    __shared__ _Float16 As[128 * 32];   // [row][k] row-major, 64B rows
    __shared__ _Float16 Bs[128 * 32];

    const int m0 = bm * 128, n0 = bn * 128;

    f32x4 acc[4][4];
#pragma unroll
    for (int m = 0; m < 4; ++m)
#pragma unroll
        for (int n = 0; n < 4; ++n) acc[m][n] = (f32x4)0.f;

    float biasv[4];
#pragma unroll
    for (int n = 0; n < 4; ++n)
        biasv[n] = bias[n0 + wc * 64 + n * 16 + fr];

    const int c0 = t, c1 = t + 256;   // 16B chunk ids within the 8KB tile

    for (int k0 = 0; k0 < Kd; k0 += 32) {
        __syncthreads();   // previous iter's LDS reads done
        {
            const _Float16* Ab = Ah + (size_t)m0 * Kd + k0;
            const _Float16* Bb = Wh + (size_t)n0 * Kd + k0;
            __builtin_amdgcn_global_load_lds(GLP(Ab + (c0 >> 2) * Kd + (c0 & 3) * 8),
                                             LDSP((char*)As + c0 * 16), 16, 0, 0);
            __builtin_amdgcn_global_load_lds(GLP(Ab + (c1 >> 2) * Kd + (c1 & 3) * 8),
                                             LDSP((char*)As + c1 * 16), 16, 0, 0);
            __builtin_amdgcn_global_load_lds(GLP(Bb + (c0 >> 2) * Kd + (c0 & 3) * 8),
                                             LDSP((char*)Bs + c0 * 16), 16, 0, 0);
            __builtin_amdgcn_global_load_lds(GLP(Bb + (c1 >> 2) * Kd + (c1 & 3) * 8),
                                             LDSP((char*)Bs + c1 * 16), 16, 0, 0);
        }
        __syncthreads();   // vmcnt(0) drained before barrier by compiler

        half8 a[4], b[4];
#pragma unroll
        for (int m = 0; m < 4; ++m)
            a[m] = *(const half8*)&As[(wr * 64 + m * 16 + fr) * 32 + fq * 8];
#pragma unroll
        for (int n = 0; n < 4; ++n)
            b[n] = *(const half8*)&Bs[(wc * 64 + n * 16 + fr) * 32 + fq * 8];
#pragma unroll
        for (int m = 0; m < 4; ++m)
#pragma unroll
            for (int n = 0; n < 4; ++n)
                acc[m][n] = __builtin_amdgcn_mfma_f32_16x16x32_f16(a[m], b[n], acc[m][n], 0, 0, 0);
    }

    // epilogue: bias, scatter to Q/K/V (f16). BN=128 never straddles Q/K/V.
    const int which = n0 / dim;            // 0,1,2
    const int offb  = n0 - which * dim;    // col base within dim
    _Float16* dst = (which == 0) ? Qo : (which == 1) ? Ko : Vo;
#pragma unroll
    for (int m = 0; m < 4; ++m) {
#pragma unroll
        for (int n = 0; n < 4; ++n) {
            int gc = offb + wc * 64 + n * 16 + fr;
#pragma unroll
            for (int j = 0; j < 4; ++j) {
                int gm = m0 + wr * 64 + m * 16 + fq * 4 + j;
                dst[(size_t)gm * dim + gc] = (_Float16)(acc[m][n][j] + biasv[n]);
            }
        }
    }
}

// ---------------------------------------------------------------------------
// Flash attention: one block per (seq b, head h, q-tile of 64 rows).
// f16 inputs (converted to fp32 in LDS); fp32 math; K staged transposed;
// P reuses the K buffer; online softmax.
// ---------------------------------------------------------------------------
__global__ __launch_bounds__(256)
void attn_kernel(const _Float16* __restrict__ Q, const _Float16* __restrict__ K,
                 const _Float16* __restrict__ V, const int* __restrict__ cu,
                 float* __restrict__ out, int dim, int H)
{
    const int bh = blockIdx.x;
    const int b  = bh / H;
    const int h  = bh - b * H;
    const int qt = blockIdx.y;

    const int s0 = cu[b], s1 = cu[b + 1];
    const int L  = s1 - s0;
    if (qt * 64 >= L) return;

    const int t  = threadIdx.x;
    const int tx = t & 15;
    const int ty = t >> 4;

    __shared__ float Qts[64][68];   // [d][r]
    __shared__ float KPs[64][68];   // phase A: Kt [d][c]; phase B: P [r][k]
    __shared__ float Vs [64][68];   // [k][d]

    // ---- stage Q transposed ----
    {
        int r = t & 63, dgrp = t >> 6;
        int qrow = qt * 64 + r;
        const _Float16* src = Q + (size_t)(s0 + qrow) * dim + h * HD + dgrp * 16;
#pragma unroll
        for (int q4 = 0; q4 < 4; ++q4) {
            float vx = 0.f, vy = 0.f, vz = 0.f, vw = 0.f;
            if (qrow < L) {
                half4v v = *(const half4v*)(src + q4 * 4);
                vx = (float)v.x; vy = (float)v.y; vz = (float)v.z; vw = (float)v.w;
            }
            int d = dgrp * 16 + q4 * 4;
            Qts[d + 0][r] = vx; Qts[d + 1][r] = vy;
            Qts[d + 2][r] = vz; Qts[d + 3][r] = vw;
        }
    }

    float o[4][4];
    float m_run[4], l_run[4];
#pragma unroll
    for (int i = 0; i < 4; ++i) {
        m_run[i] = -3.0e38f; l_run[i] = 0.f;
#pragma unroll
        for (int j = 0; j < 4; ++j) o[i][j] = 0.f;
    }

    const float scale = rsqrtf((float)HD);
    const int nkt = (L + 63) >> 6;

    for (int kt = 0; kt < nkt; ++kt) {
        __syncthreads();

        // ---- stage K (transposed) and V ----
        {
            int c = t & 63, dgrp = t >> 6;
            int krow = kt * 64 + c;
            const _Float16* srcK = K + (size_t)(s0 + krow) * dim + h * HD + dgrp * 16;
#pragma unroll
            for (int q4 = 0; q4 < 4; ++q4) {
                float vx = 0.f, vy = 0.f, vz = 0.f, vw = 0.f;
                if (krow < L) {
                    half4v v = *(const half4v*)(srcK + q4 * 4);
                    vx = (float)v.x; vy = (float)v.y; vz = (float)v.z; vw = (float)v.w;
                }
                int d = dgrp * 16 + q4 * 4;
                KPs[d + 0][c] = vx; KPs[d + 1][c] = vy;
                KPs[d + 2][c] = vz; KPs[d + 3][c] = vw;
            }
            int kv = t >> 2, dq = (t & 3) * 16;
            int vrow = kt * 64 + kv;
            const _Float16* srcV = V + (size_t)(s0 + vrow) * dim + h * HD + dq;
#pragma unroll
            for (int q4 = 0; q4 < 4; ++q4) {
                float4 v = make_float4(0.f, 0.f, 0.f, 0.f);
                if (vrow < L) {
                    half4v hv = *(const half4v*)(srcV + q4 * 4);
                    v.x = (float)hv.x; v.y = (float)hv.y;
                    v.z = (float)hv.z; v.w = (float)hv.w;
                }
                *(float4*)&Vs[kv][dq + q4 * 4] = v;
            }
        }
        __syncthreads();

        // ---- S = scale * Q K^T ----
        float s[4][4];
#pragma unroll
        for (int i = 0; i < 4; ++i)
#pragma unroll
            for (int j = 0; j < 4; ++j) s[i][j] = 0.f;

        for (int d = 0; d < 64; ++d) {
            float4 qv = *(const float4*)&Qts[d][ty * 4];
            float4 kv = *(const float4*)&KPs[d][tx * 4];
            float qa[4] = {qv.x, qv.y, qv.z, qv.w};
            float ka[4] = {kv.x, kv.y, kv.z, kv.w};
#pragma unroll
            for (int i = 0; i < 4; ++i)
#pragma unroll
                for (int j = 0; j < 4; ++j)
                    s[i][j] = fmaf(qa[i], ka[j], s[i][j]);
        }
#pragma unroll
        for (int i = 0; i < 4; ++i)
#pragma unroll
            for (int j = 0; j < 4; ++j) {
                int kg = kt * 64 + tx * 4 + j;
                s[i][j] = (kg < L) ? s[i][j] * scale : -1.0e30f;
            }

        // ---- online softmax ----
        float fac[4];
#pragma unroll
        for (int i = 0; i < 4; ++i) {
            float mx = fmaxf(fmaxf(s[i][0], s[i][1]), fmaxf(s[i][2], s[i][3]));
            mx = fmaxf(mx, __shfl_xor(mx, 1));
            mx = fmaxf(mx, __shfl_xor(mx, 2));
            mx = fmaxf(mx, __shfl_xor(mx, 4));
            mx = fmaxf(mx, __shfl_xor(mx, 8));
            float mnew = fmaxf(m_run[i], mx);
            fac[i] = __expf(m_run[i] - mnew);
            m_run[i] = mnew;
            float ls = 0.f;
#pragma unroll
            for (int j = 0; j < 4; ++j) {
                s[i][j] = __expf(s[i][j] - mnew);
                ls += s[i][j];
            }
            ls += __shfl_xor(ls, 1);
            ls += __shfl_xor(ls, 2);
            ls += __shfl_xor(ls, 4);
            ls += __shfl_xor(ls, 8);
            l_run[i] = l_run[i] * fac[i] + ls;
#pragma unroll
            for (int j = 0; j < 4; ++j) o[i][j] *= fac[i];
        }

        __syncthreads();

        // ---- write P into KPs as [r][k] ----
#pragma unroll
        for (int i = 0; i < 4; ++i)
            *(float4*)&KPs[ty * 4 + i][tx * 4] = *(float4*)&s[i][0];

        __syncthreads();

        // ---- O += P @ V ----
        for (int k = 0; k < 64; ++k) {
            float4 vv = *(const float4*)&Vs[k][tx * 4];
            float va[4] = {vv.x, vv.y, vv.z, vv.w};
            float pr[4];
#pragma unroll
            for (int i = 0; i < 4; ++i) pr[i] = KPs[ty * 4 + i][k];
#pragma unroll
            for (int i = 0; i < 4; ++i)
#pragma unroll
                for (int j = 0; j < 4; ++j)
                    o[i][j] = fmaf(pr[i], va[j], o[i][j]);
        }
    }

    // ---- normalize + store ----
#pragma unroll
    for (int i = 0; i < 4; ++i) {
        int qrow = qt * 64 + ty * 4 + i;
        if (qrow >= L) continue;
        float inv = 1.0f / l_run[i];
        float4 c;
        c.x = o[i][0] * inv; c.y = o[i][1] * inv;
        c.z = o[i][2] * inv; c.w = o[i][3] * inv;
        *(float4*)(out + (size_t)(s0 + qrow) * dim + h * HD + tx * 4) = c;
    }
}

// ---------------------------------------------------------------------------
extern "C" void kernel_launch(void* const* d_in, const int* in_sizes, int n_in,
                              void* d_out, int out_size, void* d_ws, size_t ws_size,
                              hipStream_t stream)
{
    const float* hs   = (const float*)d_in[0];
    const float* W    = (const float*)d_in[1];
    const float* bias = (const float*)d_in[2];
    const int*   cu   = (const int*)d_in[3];

    const int dim3x = in_sizes[2];        // 3072
    const int dim   = dim3x / 3;          // 1024
    const int nnz   = in_sizes[0] / dim;  // 8704
    const int B     = in_sizes[3] - 1;    // 16
    const int H     = dim / HD;           // 16
    const size_t nA = (size_t)nnz * dim;
    const size_t nW = (size_t)dim3x * dim;

    _Float16* Ah = (_Float16*)d_ws;
    _Float16* Wh = Ah + nA;
    _Float16* Qh = Wh + nW;
    _Float16* Kh = Qh + nA;
    _Float16* Vh = Kh + nA;

    cvt_kernel<<<1024, 256, 0, stream>>>(hs, W, Ah, Wh, (int)(nA / 4), (int)(nW / 4));

    dim3 g1(nnz / 128, dim3x / 128);
    qkv_gemm_kernel<<<g1, 256, 0, stream>>>(Ah, Wh, bias, Qh, Kh, Vh, dim, dim);

    dim3 g2(B * H, (nnz + 63) / 64);
    attn_kernel<<<g2, 256, 0, stream>>>(Qh, Kh, Vh, cu, (float*)d_out, dim, H);
}

// Round 5
// 297.416 us; speedup vs baseline: 4.0807x; 1.9629x over previous
//
#include <hip/hip_runtime.h>
#include <math.h>

// BertFlashSelfAttention (varlen, H=16, D=64)
// Phase 0: fp32 -> f16 convert (hidden, Wqkv)
// Phase 1: QKV GEMM via mfma_f32_16x16x32_f16 (validated r3), Q/K/V f16 in ws
// Phase 2: MFMA flash attention: QBLK=128 (4 waves x 32 q-rows), KVBLK=64,
//          f16 MFMA for QK^T and PV, fp32 online softmax. -> d_out fp32

#define HD 64

typedef _Float16 half8 __attribute__((ext_vector_type(8)));
typedef _Float16 half4v __attribute__((ext_vector_type(4)));
typedef float f32x4 __attribute__((ext_vector_type(4)));

#define GLP(p) ((__attribute__((address_space(1))) void*)(p))
#define LDSP(p) ((__attribute__((address_space(3))) void*)(p))

// ---------------------------------------------------------------------------
// fp32 -> f16 conversion (grid-stride, float4 in / half4 out)
// ---------------------------------------------------------------------------
__global__ __launch_bounds__(256)
void cvt_kernel(const float* __restrict__ A, const float* __restrict__ W,
                _Float16* __restrict__ Ah, _Float16* __restrict__ Wh,
                int nA4, int nW4)
{
    int total = nA4 + nW4;
    for (int i = blockIdx.x * blockDim.x + threadIdx.x; i < total;
         i += gridDim.x * blockDim.x) {
        const float* src; _Float16* dst; int j;
        if (i < nA4) { src = A; dst = Ah; j = i; }
        else         { src = W; dst = Wh; j = i - nA4; }
        float4 v = *(const float4*)(src + (size_t)j * 4);
        half4v h;
        h.x = (_Float16)v.x; h.y = (_Float16)v.y;
        h.z = (_Float16)v.z; h.w = (_Float16)v.w;
        *(half4v*)(dst + (size_t)j * 4) = h;
    }
}

// ---------------------------------------------------------------------------
// QKV GEMM (unchanged from r3, validated): C = A*W^T + bias, f16 MFMA.
// ---------------------------------------------------------------------------
__global__ __launch_bounds__(256)
void qkv_gemm_kernel(const _Float16* __restrict__ Ah, const _Float16* __restrict__ Wh,
                     const float* __restrict__ bias,
                     _Float16* __restrict__ Qo, _Float16* __restrict__ Ko,
                     _Float16* __restrict__ Vo,
                     int Kd, int dim)
{
    const int bm = blockIdx.x, bn = blockIdx.y;
    const int t = threadIdx.x;
    const int wid = t >> 6, lane = t & 63;
    const int wr = wid >> 1, wc = wid & 1;
    const int fr = lane & 15, fq = lane >> 4;

    __shared__ _Float16 As[128 * 32];
    __shared__ _Float16 Bs[128 * 32];

    const int m0 = bm * 128, n0 = bn * 128;

    f32x4 acc[4][4];
#pragma unroll
    for (int m = 0; m < 4; ++m)
#pragma unroll
        for (int n = 0; n < 4; ++n) acc[m][n] = (f32x4)0.f;

    float biasv[4];
#pragma unroll
    for (int n = 0; n < 4; ++n)
        biasv[n] = bias[n0 + wc * 64 + n * 16 + fr];

    const int c0 = t, c1 = t + 256;

    for (int k0 = 0; k0 < Kd; k0 += 32) {
        __syncthreads();
        {
            const _Float16* Ab = Ah + (size_t)m0 * Kd + k0;
            const _Float16* Bb = Wh + (size_t)n0 * Kd + k0;
            __builtin_amdgcn_global_load_lds(GLP(Ab + (c0 >> 2) * Kd + (c0 & 3) * 8),
                                             LDSP((char*)As + c0 * 16), 16, 0, 0);
            __builtin_amdgcn_global_load_lds(GLP(Ab + (c1 >> 2) * Kd + (c1 & 3) * 8),
                                             LDSP((char*)As + c1 * 16), 16, 0, 0);
            __builtin_amdgcn_global_load_lds(GLP(Bb + (c0 >> 2) * Kd + (c0 & 3) * 8),
                                             LDSP((char*)Bs + c0 * 16), 16, 0, 0);
            __builtin_amdgcn_global_load_lds(GLP(Bb + (c1 >> 2) * Kd + (c1 & 3) * 8),
                                             LDSP((char*)Bs + c1 * 16), 16, 0, 0);
        }
        __syncthreads();

        half8 a[4], b[4];
#pragma unroll
        for (int m = 0; m < 4; ++m)
            a[m] = *(const half8*)&As[(wr * 64 + m * 16 + fr) * 32 + fq * 8];
#pragma unroll
        for (int n = 0; n < 4; ++n)
            b[n] = *(const half8*)&Bs[(wc * 64 + n * 16 + fr) * 32 + fq * 8];
#pragma unroll
        for (int m = 0; m < 4; ++m)
#pragma unroll
            for (int n = 0; n < 4; ++n)
                acc[m][n] = __builtin_amdgcn_mfma_f32_16x16x32_f16(a[m], b[n], acc[m][n], 0, 0, 0);
    }

    const int which = n0 / dim;
    const int offb  = n0 - which * dim;
    _Float16* dst = (which == 0) ? Qo : (which == 1) ? Ko : Vo;
#pragma unroll
    for (int m = 0; m < 4; ++m) {
#pragma unroll
        for (int n = 0; n < 4; ++n) {
            int gc = offb + wc * 64 + n * 16 + fr;
#pragma unroll
            for (int j = 0; j < 4; ++j) {
                int gm = m0 + wr * 64 + m * 16 + fq * 4 + j;
                dst[(size_t)gm * dim + gc] = (_Float16)(acc[m][n][j] + biasv[n]);
            }
        }
    }
}

// ---------------------------------------------------------------------------
// MFMA flash attention.
// Block: 256 thr = 4 waves; wave w owns q-rows [qt*128 + w*32, +32).
// Per KV tile (64 rows): K staged linear-LDS via global_load_lds with
// XOR-pre-swizzled SOURCE (read applies same XOR); V reg-staged transposed
// into padded Vt[d][kv]; P roundtrips through per-wave padded LDS.
// ---------------------------------------------------------------------------
__global__ __launch_bounds__(256)
void attn_kernel(const _Float16* __restrict__ Q, const _Float16* __restrict__ K,
                 const _Float16* __restrict__ V, const int* __restrict__ cu,
                 float* __restrict__ out, int dim, int H)
{
    const int bh = blockIdx.x;
    const int b  = bh / H;
    const int h  = bh - b * H;
    const int qt = blockIdx.y;

    const int s0 = cu[b];
    const int L  = cu[b + 1] - s0;
    if (qt * 128 >= L) return;

    const int t    = threadIdx.x;
    const int wid  = t >> 6, lane = t & 63;
    const int fr   = lane & 15, fq = lane >> 4;

    __shared__ _Float16 Ks[64 * 64];      // 8 KB, swizzled 128B rows
    __shared__ _Float16 Vt[64 * 72];      // 9 KB, [d][kv] padded
    __shared__ _Float16 Ps[4][32 * 72];   // 18 KB, per-wave P [q][kv] padded

    _Float16* Psw = &Ps[wid][0];

    // ---- Q fragments in registers, scale 1/8 folded in (exact in f16) ----
    half8 aq[2][2];
#pragma unroll
    for (int qm = 0; qm < 2; ++qm)
#pragma unroll
        for (int kc = 0; kc < 2; ++kc) {
            int qrow = qt * 128 + wid * 32 + qm * 16 + fr;
            int qr = (qrow < L) ? qrow : 0;
            half8 v = *(const half8*)(Q + (size_t)(s0 + qr) * dim + h * HD + kc * 32 + fq * 8);
#pragma unroll
            for (int i = 0; i < 8; ++i) v[i] = v[i] * (_Float16)0.125f;
            aq[qm][kc] = v;
        }

    f32x4 o[2][4];
    float m_run[2][4], l_run[2][4];
#pragma unroll
    for (int qm = 0; qm < 2; ++qm) {
#pragma unroll
        for (int n = 0; n < 4; ++n) o[qm][n] = (f32x4)0.f;
#pragma unroll
        for (int j = 0; j < 4; ++j) { m_run[qm][j] = -3.0e38f; l_run[qm][j] = 0.f; }
    }

    const int nkt = (L + 63) >> 6;
    const int vkv = t & 63, vdc = t >> 6;   // V staging: 1 kv row, 16 d per thread

    for (int kt = 0; kt < nkt; ++kt) {
        __syncthreads();   // prev tile's Ks/Vt reads done

        // ---- stage K: linear LDS dest, XOR-swizzled global source ----
#pragma unroll
        for (int cc = 0; cc < 2; ++cc) {
            int c    = wid * 2 + cc;            // chunk 0..7 (1 KB each)
            int phys = c * 1024 + lane * 16;    // linear LDS byte
            int r    = phys >> 7;               // kv row (128B rows)
            int lb   = (phys & 127) ^ ((r & 7) << 4);  // logical byte in row
            int krow = kt * 64 + r;
            int kr   = (krow < L) ? krow : 0;
            const char* src = (const char*)K + ((size_t)(s0 + kr) * dim + h * HD) * 2 + lb;
            __builtin_amdgcn_global_load_lds(GLP(src), LDSP((char*)Ks + phys), 16, 0, 0);
        }
        // ---- stage V transposed: Vt[d][kv] ----
        {
            int vrow = kt * 64 + vkv;
            int vr   = (vrow < L) ? vrow : 0;
            const _Float16* sv = V + (size_t)(s0 + vr) * dim + h * HD + vdc * 16;
            half8 v0 = *(const half8*)(sv);
            half8 v1 = *(const half8*)(sv + 8);
#pragma unroll
            for (int i = 0; i < 8; ++i) {
                Vt[(vdc * 16 + i) * 72 + vkv]     = v0[i];
                Vt[(vdc * 16 + 8 + i) * 72 + vkv] = v1[i];
            }
        }
        __syncthreads();

        // ---- S = (Q/8) K^T : 16 MFMA per wave ----
        f32x4 s[2][4];
#pragma unroll
        for (int qm = 0; qm < 2; ++qm)
#pragma unroll
            for (int n = 0; n < 4; ++n) s[qm][n] = (f32x4)0.f;

#pragma unroll
        for (int n = 0; n < 4; ++n)
#pragma unroll
            for (int kc = 0; kc < 2; ++kc) {
                const half8 bk = *(const half8*)((const char*)Ks +
                    ((n * 16 + fr) << 7) + (((kc << 6) + (fq << 4)) ^ ((fr & 7) << 4)));
                s[0][n] = __builtin_amdgcn_mfma_f32_16x16x32_f16(aq[0][kc], bk, s[0][n], 0, 0, 0);
                s[1][n] = __builtin_amdgcn_mfma_f32_16x16x32_f16(aq[1][kc], bk, s[1][n], 0, 0, 0);
            }

        // ---- mask partial tile (lengths are x64, so normally skipped) ----
        int ksz = L - kt * 64;
        if (ksz < 64) {
#pragma unroll
            for (int n = 0; n < 4; ++n)
                if (n * 16 + fr >= ksz) {
#pragma unroll
                    for (int qm = 0; qm < 2; ++qm)
#pragma unroll
                        for (int j = 0; j < 4; ++j) s[qm][n][j] = -1.0e30f;
                }
        }

        // ---- online softmax (rows live on 16 lanes sharing fq) + P write ----
#pragma unroll
        for (int qm = 0; qm < 2; ++qm)
#pragma unroll
            for (int j = 0; j < 4; ++j) {
                float mx = fmaxf(fmaxf(s[qm][0][j], s[qm][1][j]),
                                 fmaxf(s[qm][2][j], s[qm][3][j]));
                mx = fmaxf(mx, __shfl_xor(mx, 1));
                mx = fmaxf(mx, __shfl_xor(mx, 2));
                mx = fmaxf(mx, __shfl_xor(mx, 4));
                mx = fmaxf(mx, __shfl_xor(mx, 8));
                float mnew = fmaxf(m_run[qm][j], mx);
                float fac  = __expf(m_run[qm][j] - mnew);
                m_run[qm][j] = mnew;
                float p0 = __expf(s[qm][0][j] - mnew);
                float p1 = __expf(s[qm][1][j] - mnew);
                float p2 = __expf(s[qm][2][j] - mnew);
                float p3 = __expf(s[qm][3][j] - mnew);
                float ls = p0 + p1 + p2 + p3;
                ls += __shfl_xor(ls, 1);
                ls += __shfl_xor(ls, 2);
                ls += __shfl_xor(ls, 4);
                ls += __shfl_xor(ls, 8);
                l_run[qm][j] = l_run[qm][j] * fac + ls;
                o[qm][0][j] *= fac; o[qm][1][j] *= fac;
                o[qm][2][j] *= fac; o[qm][3][j] *= fac;
                int qloc = qm * 16 + fq * 4 + j;
                Psw[qloc * 72 +  0 + fr] = (_Float16)p0;
                Psw[qloc * 72 + 16 + fr] = (_Float16)p1;
                Psw[qloc * 72 + 32 + fr] = (_Float16)p2;
                Psw[qloc * 72 + 48 + fr] = (_Float16)p3;
            }
        __syncthreads();   // P visible (also keeps Vt protected until here)

        // ---- O += P V : 16 MFMA per wave ----
#pragma unroll
        for (int kc = 0; kc < 2; ++kc) {
            half8 ap0 = *(const half8*)&Psw[(0 * 16 + fr) * 72 + kc * 32 + fq * 8];
            half8 ap1 = *(const half8*)&Psw[(1 * 16 + fr) * 72 + kc * 32 + fq * 8];
#pragma unroll
            for (int n2 = 0; n2 < 4; ++n2) {
                half8 bv = *(const half8*)&Vt[(n2 * 16 + fr) * 72 + kc * 32 + fq * 8];
                o[0][n2] = __builtin_amdgcn_mfma_f32_16x16x32_f16(ap0, bv, o[0][n2], 0, 0, 0);
                o[1][n2] = __builtin_amdgcn_mfma_f32_16x16x32_f16(ap1, bv, o[1][n2], 0, 0, 0);
            }
        }
    }

    // ---- normalize + store ----
#pragma unroll
    for (int qm = 0; qm < 2; ++qm)
#pragma unroll
        for (int j = 0; j < 4; ++j) {
            int qrow = qt * 128 + wid * 32 + qm * 16 + fq * 4 + j;
            if (qrow >= L) continue;
            float inv = 1.0f / l_run[qm][j];
#pragma unroll
            for (int n2 = 0; n2 < 4; ++n2)
                out[(size_t)(s0 + qrow) * dim + h * HD + n2 * 16 + fr] = o[qm][n2][j] * inv;
        }
}

// ---------------------------------------------------------------------------
extern "C" void kernel_launch(void* const* d_in, const int* in_sizes, int n_in,
                              void* d_out, int out_size, void* d_ws, size_t ws_size,
                              hipStream_t stream)
{
    const float* hs   = (const float*)d_in[0];
    const float* W    = (const float*)d_in[1];
    const float* bias = (const float*)d_in[2];
    const int*   cu   = (const int*)d_in[3];

    const int dim3x = in_sizes[2];        // 3072
    const int dim   = dim3x / 3;          // 1024
    const int nnz   = in_sizes[0] / dim;  // 8704
    const int B     = in_sizes[3] - 1;    // 16
    const int H     = dim / HD;           // 16
    const size_t nA = (size_t)nnz * dim;
    const size_t nW = (size_t)dim3x * dim;

    _Float16* Ah = (_Float16*)d_ws;
    _Float16* Wh = Ah + nA;
    _Float16* Qh = Wh + nW;
    _Float16* Kh = Qh + nA;
    _Float16* Vh = Kh + nA;

    cvt_kernel<<<1024, 256, 0, stream>>>(hs, W, Ah, Wh, (int)(nA / 4), (int)(nW / 4));

    dim3 g1(nnz / 128, dim3x / 128);
    qkv_gemm_kernel<<<g1, 256, 0, stream>>>(Ah, Wh, bias, Qh, Kh, Vh, dim, dim);

    dim3 g2(B * H, (nnz + 127) / 128);
    attn_kernel<<<g2, 256, 0, stream>>>(Qh, Kh, Vh, cu, (float*)d_out, dim, H);
}

// Round 8
// 259.647 us; speedup vs baseline: 4.6743x; 1.1455x over previous
//
#include <hip/hip_runtime.h>
#include <math.h>

// BertFlashSelfAttention (varlen, H=16, D=64)
// Phase 0: fp32 -> f16 convert (hidden, Wqkv)
// Phase 1: QKV GEMM via mfma_f32_16x16x32_f16 (validated r3), Q/K/V f16 in ws
// Phase 2: MFMA flash attention, swapped-QK^T softmax (S^T = mfma(K,Q)),
//          heavy-first 1-D scheduling, exp2 softmax, 2 barriers/tile.

#define HD 64

typedef _Float16 half8 __attribute__((ext_vector_type(8)));
typedef _Float16 half4v __attribute__((ext_vector_type(4)));
typedef float f32x4 __attribute__((ext_vector_type(4)));

#define GLP(p) ((__attribute__((address_space(1))) void*)(p))
#define LDSP(p) ((__attribute__((address_space(3))) void*)(p))

// ---------------------------------------------------------------------------
// fp32 -> f16 conversion (grid-stride, float4 in / half4 out)
// ---------------------------------------------------------------------------
__global__ __launch_bounds__(256)
void cvt_kernel(const float* __restrict__ A, const float* __restrict__ W,
                _Float16* __restrict__ Ah, _Float16* __restrict__ Wh,
                int nA4, int nW4)
{
    int total = nA4 + nW4;
    for (int i = blockIdx.x * blockDim.x + threadIdx.x; i < total;
         i += gridDim.x * blockDim.x) {
        const float* src; _Float16* dst; int j;
        if (i < nA4) { src = A; dst = Ah; j = i; }
        else         { src = W; dst = Wh; j = i - nA4; }
        float4 v = *(const float4*)(src + (size_t)j * 4);
        half4v h;
        h.x = (_Float16)v.x; h.y = (_Float16)v.y;
        h.z = (_Float16)v.z; h.w = (_Float16)v.w;
        *(half4v*)(dst + (size_t)j * 4) = h;
    }
}

// ---------------------------------------------------------------------------
// QKV GEMM (unchanged, validated r3/r5): C = A*W^T + bias, f16 MFMA.
// ---------------------------------------------------------------------------
__global__ __launch_bounds__(256)
void qkv_gemm_kernel(const _Float16* __restrict__ Ah, const _Float16* __restrict__ Wh,
                     const float* __restrict__ bias,
                     _Float16* __restrict__ Qo, _Float16* __restrict__ Ko,
                     _Float16* __restrict__ Vo,
                     int Kd, int dim)
{
    const int bm = blockIdx.x, bn = blockIdx.y;
    const int t = threadIdx.x;
    const int wid = t >> 6, lane = t & 63;
    const int wr = wid >> 1, wc = wid & 1;
    const int fr = lane & 15, fq = lane >> 4;

    __shared__ _Float16 As[128 * 32];
    __shared__ _Float16 Bs[128 * 32];

    const int m0 = bm * 128, n0 = bn * 128;

    f32x4 acc[4][4];
#pragma unroll
    for (int m = 0; m < 4; ++m)
#pragma unroll
        for (int n = 0; n < 4; ++n) acc[m][n] = (f32x4)0.f;

    float biasv[4];
#pragma unroll
    for (int n = 0; n < 4; ++n)
        biasv[n] = bias[n0 + wc * 64 + n * 16 + fr];

    const int c0 = t, c1 = t + 256;

    for (int k0 = 0; k0 < Kd; k0 += 32) {
        __syncthreads();
        {
            const _Float16* Ab = Ah + (size_t)m0 * Kd + k0;
            const _Float16* Bb = Wh + (size_t)n0 * Kd + k0;
            __builtin_amdgcn_global_load_lds(GLP(Ab + (c0 >> 2) * Kd + (c0 & 3) * 8),
                                             LDSP((char*)As + c0 * 16), 16, 0, 0);
            __builtin_amdgcn_global_load_lds(GLP(Ab + (c1 >> 2) * Kd + (c1 & 3) * 8),
                                             LDSP((char*)As + c1 * 16), 16, 0, 0);
            __builtin_amdgcn_global_load_lds(GLP(Bb + (c0 >> 2) * Kd + (c0 & 3) * 8),
                                             LDSP((char*)Bs + c0 * 16), 16, 0, 0);
            __builtin_amdgcn_global_load_lds(GLP(Bb + (c1 >> 2) * Kd + (c1 & 3) * 8),
                                             LDSP((char*)Bs + c1 * 16), 16, 0, 0);
        }
        __syncthreads();

        half8 a[4], b[4];
#pragma unroll
        for (int m = 0; m < 4; ++m)
            a[m] = *(const half8*)&As[(wr * 64 + m * 16 + fr) * 32 + fq * 8];
#pragma unroll
        for (int n = 0; n < 4; ++n)
            b[n] = *(const half8*)&Bs[(wc * 64 + n * 16 + fr) * 32 + fq * 8];
#pragma unroll
        for (int m = 0; m < 4; ++m)
#pragma unroll
            for (int n = 0; n < 4; ++n)
                acc[m][n] = __builtin_amdgcn_mfma_f32_16x16x32_f16(a[m], b[n], acc[m][n], 0, 0, 0);
    }

    const int which = n0 / dim;
    const int offb  = n0 - which * dim;
    _Float16* dst = (which == 0) ? Qo : (which == 1) ? Ko : Vo;
#pragma unroll
    for (int m = 0; m < 4; ++m) {
#pragma unroll
        for (int n = 0; n < 4; ++n) {
            int gc = offb + wc * 64 + n * 16 + fr;
#pragma unroll
            for (int j = 0; j < 4; ++j) {
                int gm = m0 + wr * 64 + m * 16 + fq * 4 + j;
                dst[(size_t)gm * dim + gc] = (_Float16)(acc[m][n][j] + biasv[n]);
            }
        }
    }
}

// ---------------------------------------------------------------------------
// MFMA flash attention, swapped-QK^T softmax.
// 1-D grid of work items w = (wq, h); wq scans seqs in REVERSED b order
// (ascending-length input => longest-first) over ceil(L/128) q-tiles.
// Block: 4 waves x 32 q-rows. KVBLK=64.
// S^T = mfma(K,Q): lane (fq,fr) reg j of tile [mt][nt] holds
//   S[q = nt*16+fr][kv = mt*16+fq*4+j]  -> row reduce = in-reg max + 2 shfl.
// P written kv-contiguous (b64); PV identical to r5. fac/l cross-lane via Fs.
// ---------------------------------------------------------------------------
__global__ __launch_bounds__(256)
void attn_kernel(const _Float16* __restrict__ Q, const _Float16* __restrict__ K,
                 const _Float16* __restrict__ V, const int* __restrict__ cu,
                 float* __restrict__ out, int dim, int H, int B)
{
    const int w  = blockIdx.x;
    const int h  = w & (H - 1);
    const int wq = w / H;

    // heavy-first schedule: reversed-b flat scan (uniform scalar loop)
    int b = -1, qt = 0, acc = 0;
    for (int i = B - 1; i >= 0; --i) {
        int Li = cu[i + 1] - cu[i];
        int nq = (Li + 127) >> 7;
        if (wq >= acc && wq < acc + nq) { b = i; qt = wq - acc; }
        acc += nq;
    }
    if (b < 0) return;

    const int s0 = cu[b];
    const int L  = cu[b + 1] - s0;

    const int t    = threadIdx.x;
    const int wid  = t >> 6, lane = t & 63;
    const int fr   = lane & 15, fq = lane >> 4;

    __shared__ _Float16 Ks[64 * 64];      // 8 KB, swizzled 128B rows
    __shared__ _Float16 Vt[64 * 72];      // 9 KB, [d][kv] padded
    __shared__ _Float16 Ps[4][32 * 72];   // 18 KB, per-wave P [q][kv] padded
    __shared__ float    Fs[4][32];        // per-wave fac / final l

    _Float16* Psw = &Ps[wid][0];
    float*    Fsw = &Fs[wid][0];

    // ---- Q fragments in registers; fold scale*log2(e) (exp2 softmax) ----
    const _Float16 qscale = (_Float16)(0.125f * 1.44269504f);
    half8 aq[2][2];
#pragma unroll
    for (int nt = 0; nt < 2; ++nt)
#pragma unroll
        for (int kc = 0; kc < 2; ++kc) {
            int qrow = qt * 128 + wid * 32 + nt * 16 + fr;
            int qr = (qrow < L) ? qrow : 0;
            half8 v = *(const half8*)(Q + (size_t)(s0 + qr) * dim + h * HD + kc * 32 + fq * 8);
#pragma unroll
            for (int i = 0; i < 8; ++i) v[i] = v[i] * qscale;
            aq[nt][kc] = v;
        }

    f32x4 o[2][4];
    float m2[2], l2[2];
#pragma unroll
    for (int qm = 0; qm < 2; ++qm)
#pragma unroll
        for (int n = 0; n < 4; ++n) o[qm][n] = (f32x4)0.f;
    m2[0] = m2[1] = -3.0e38f;
    l2[0] = l2[1] = 0.f;

    const int nkt = (L + 63) >> 6;
    const int vu = t & 31, vdc = t >> 5;   // V staging: kv pair 2u,2u+1; d = vdc*8..+8

    for (int kt = 0; kt < nkt; ++kt) {
        __syncthreads();   // all waves' Ks/Vt reads of prev tile done

        // ---- stage K: linear LDS dest, XOR-swizzled global source ----
#pragma unroll
        for (int cc = 0; cc < 2; ++cc) {
            int c    = wid * 2 + cc;            // chunk 0..7 (1 KB each)
            int phys = c * 1024 + lane * 16;    // linear LDS byte
            int r    = phys >> 7;               // kv row (128B rows)
            int lb   = (phys & 127) ^ ((r & 7) << 4);
            int krow = kt * 64 + r;
            int kr   = (krow < L) ? krow : 0;
            const char* src = (const char*)K + ((size_t)(s0 + kr) * dim + h * HD) * 2 + lb;
            __builtin_amdgcn_global_load_lds(GLP(src), LDSP((char*)Ks + phys), 16, 0, 0);
        }
        // ---- stage V transposed: Vt[d][kv], packed b32 writes ----
        {
            int k0r = kt * 64 + vu * 2;
            int r0 = (k0r     < L) ? k0r     : 0;
            int r1 = (k0r + 1 < L) ? k0r + 1 : 0;
            half8 v0 = *(const half8*)(V + (size_t)(s0 + r0) * dim + h * HD + vdc * 8);
            half8 v1 = *(const half8*)(V + (size_t)(s0 + r1) * dim + h * HD + vdc * 8);
#pragma unroll
            for (int i = 0; i < 8; ++i) {
                union { _Float16 h[2]; unsigned u; } pk;
                pk.h[0] = v0[i]; pk.h[1] = v1[i];
                *(unsigned*)&Vt[(vdc * 8 + i) * 72 + vu * 2] = pk.u;
            }
        }
        __syncthreads();   // staged data visible

        // ---- S^T = mfma(K, Q/8'): 16 MFMA per wave ----
        f32x4 s2[4][2];
#pragma unroll
        for (int mt = 0; mt < 4; ++mt)
#pragma unroll
            for (int nt = 0; nt < 2; ++nt) s2[mt][nt] = (f32x4)0.f;

#pragma unroll
        for (int mt = 0; mt < 4; ++mt)
#pragma unroll
            for (int kc = 0; kc < 2; ++kc) {
                const half8 bk = *(const half8*)((const char*)Ks +
                    ((mt * 16 + fr) << 7) + (((kc << 6) + (fq << 4)) ^ ((fr & 7) << 4)));
                s2[mt][0] = __builtin_amdgcn_mfma_f32_16x16x32_f16(bk, aq[0][kc], s2[mt][0], 0, 0, 0);
                s2[mt][1] = __builtin_amdgcn_mfma_f32_16x16x32_f16(bk, aq[1][kc], s2[mt][1], 0, 0, 0);
            }

        // ---- mask partial tile (kv = mt*16 + fq*4 + j) ----
        int ksz = L - kt * 64;
        if (ksz < 64) {
#pragma unroll
            for (int mt = 0; mt < 4; ++mt)
#pragma unroll
                for (int j = 0; j < 4; ++j)
                    if (mt * 16 + fq * 4 + j >= ksz) {
                        s2[mt][0][j] = -1.0e30f;
                        s2[mt][1][j] = -1.0e30f;
                    }
        }

        // ---- softmax per nt (q = nt*16+fr): in-reg max + 2 shfl; exp2 ----
#pragma unroll
        for (int nt = 0; nt < 2; ++nt) {
            f32x4 mx4 = s2[0][nt];
#pragma unroll
            for (int mt = 1; mt < 4; ++mt) {
#pragma unroll
                for (int j = 0; j < 4; ++j) mx4[j] = fmaxf(mx4[j], s2[mt][nt][j]);
            }
            float mx = fmaxf(fmaxf(mx4[0], mx4[1]), fmaxf(mx4[2], mx4[3]));
            mx = fmaxf(mx, __shfl_xor(mx, 16));
            mx = fmaxf(mx, __shfl_xor(mx, 32));
            float mnew = fmaxf(m2[nt], mx);
            float facn = __builtin_exp2f(m2[nt] - mnew);
            m2[nt] = mnew;

            f32x4 sum4 = (f32x4)0.f;
#pragma unroll
            for (int mt = 0; mt < 4; ++mt) {
                half4v ph;
#pragma unroll
                for (int j = 0; j < 4; ++j) {
                    float p = __builtin_exp2f(s2[mt][nt][j] - mnew);
                    sum4[j] += p;
                    ph[j] = (_Float16)p;
                }
                // P[q = nt*16+fr][kv = mt*16 + fq*4 .. +3]  (8B write)
                *(half4v*)&Psw[(nt * 16 + fr) * 72 + mt * 16 + fq * 4] = ph;
            }
            float ls = (sum4[0] + sum4[1]) + (sum4[2] + sum4[3]);
            ls += __shfl_xor(ls, 16);
            ls += __shfl_xor(ls, 32);
            l2[nt] = l2[nt] * facn + ls;
            if (fq == 0) Fsw[nt * 16 + fr] = facn;
        }

        // ---- o-rescale: fetch fac for o-rows (q = qm*16 + fq*4 + j) ----
#pragma unroll
        for (int qm = 0; qm < 2; ++qm) {
            f32x4 fj = *(const f32x4*)&Fsw[qm * 16 + fq * 4];
#pragma unroll
            for (int n2 = 0; n2 < 4; ++n2)
#pragma unroll
                for (int j = 0; j < 4; ++j) o[qm][n2][j] *= fj[j];
        }

        // ---- O += P V : 16 MFMA per wave (Ps per-wave -> no barrier) ----
#pragma unroll
        for (int kc = 0; kc < 2; ++kc) {
            half8 ap0 = *(const half8*)&Psw[(0 * 16 + fr) * 72 + kc * 32 + fq * 8];
            half8 ap1 = *(const half8*)&Psw[(1 * 16 + fr) * 72 + kc * 32 + fq * 8];
#pragma unroll
            for (int n2 = 0; n2 < 4; ++n2) {
                half8 bv = *(const half8*)&Vt[(n2 * 16 + fr) * 72 + kc * 32 + fq * 8];
                o[0][n2] = __builtin_amdgcn_mfma_f32_16x16x32_f16(ap0, bv, o[0][n2], 0, 0, 0);
                o[1][n2] = __builtin_amdgcn_mfma_f32_16x16x32_f16(ap1, bv, o[1][n2], 0, 0, 0);
            }
        }
    }

    // ---- final l to o-row lanes via Fs, normalize + store ----
    if (fq == 0) { Fsw[fr] = l2[0]; Fsw[16 + fr] = l2[1]; }
#pragma unroll
    for (int qm = 0; qm < 2; ++qm) {
        f32x4 lj = *(const f32x4*)&Fsw[qm * 16 + fq * 4];
#pragma unroll
        for (int j = 0; j < 4; ++j) {
            int qrow = qt * 128 + wid * 32 + qm * 16 + fq * 4 + j;
            if (qrow >= L) continue;
            float inv = 1.0f / lj[j];
#pragma unroll
            for (int n2 = 0; n2 < 4; ++n2)
                out[(size_t)(s0 + qrow) * dim + h * HD + n2 * 16 + fr] = o[qm][n2][j] * inv;
        }
    }
}

// ---------------------------------------------------------------------------
extern "C" void kernel_launch(void* const* d_in, const int* in_sizes, int n_in,
                              void* d_out, int out_size, void* d_ws, size_t ws_size,
                              hipStream_t stream)
{
    const float* hs   = (const float*)d_in[0];
    const float* W    = (const float*)d_in[1];
    const float* bias = (const float*)d_in[2];
    const int*   cu   = (const int*)d_in[3];

    const int dim3x = in_sizes[2];        // 3072
    const int dim   = dim3x / 3;          // 1024
    const int nnz   = in_sizes[0] / dim;  // 8704
    const int B     = in_sizes[3] - 1;    // 16
    const int H     = dim / HD;           // 16
    const size_t nA = (size_t)nnz * dim;
    const size_t nW = (size_t)dim3x * dim;

    _Float16* Ah = (_Float16*)d_ws;
    _Float16* Wh = Ah + nA;
    _Float16* Qh = Wh + nW;
    _Float16* Kh = Qh + nA;
    _Float16* Vh = Kh + nA;

    cvt_kernel<<<1024, 256, 0, stream>>>(hs, W, Ah, Wh, (int)(nA / 4), (int)(nW / 4));

    dim3 g1(nnz / 128, dim3x / 128);
    qkv_gemm_kernel<<<g1, 256, 0, stream>>>(Ah, Wh, bias, Qh, Kh, Vh, dim, dim);

    const int maxWQ = nnz / 128 + B;      // upper bound on total q-tiles
    attn_kernel<<<maxWQ * H, 256, 0, stream>>>(Qh, Kh, Vh, cu, (float*)d_out, dim, H, B);
}

// Round 9
// 244.321 us; speedup vs baseline: 4.9675x; 1.0627x over previous
//
#include <hip/hip_runtime.h>
#include <math.h>

// BertFlashSelfAttention (varlen, H=16, D=64)
// Phase 0: fp32 -> f16 convert (hidden, Wqkv)
// Phase 1: QKV GEMM, BK=64, XOR-swizzled LDS (T2) via pre-swizzled
//          global_load_lds source; mfma_f32_16x16x32_f16.
// Phase 2: MFMA flash attention (validated r8): swapped-QK^T softmax,
//          heavy-first scheduling, exp2 softmax, 2 barriers/tile.

#define HD 64

typedef _Float16 half8 __attribute__((ext_vector_type(8)));
typedef _Float16 half4v __attribute__((ext_vector_type(4)));
typedef float f32x4 __attribute__((ext_vector_type(4)));

#define GLP(p) ((__attribute__((address_space(1))) void*)(p))
#define LDSP(p) ((__attribute__((address_space(3))) void*)(p))

// ---------------------------------------------------------------------------
// fp32 -> f16 conversion (grid-stride, float4 in / half4 out)
// ---------------------------------------------------------------------------
__global__ __launch_bounds__(256)
void cvt_kernel(const float* __restrict__ A, const float* __restrict__ W,
                _Float16* __restrict__ Ah, _Float16* __restrict__ Wh,
                int nA4, int nW4)
{
    int total = nA4 + nW4;
    for (int i = blockIdx.x * blockDim.x + threadIdx.x; i < total;
         i += gridDim.x * blockDim.x) {
        const float* src; _Float16* dst; int j;
        if (i < nA4) { src = A; dst = Ah; j = i; }
        else         { src = W; dst = Wh; j = i - nA4; }
        float4 v = *(const float4*)(src + (size_t)j * 4);
        half4v h;
        h.x = (_Float16)v.x; h.y = (_Float16)v.y;
        h.z = (_Float16)v.z; h.w = (_Float16)v.w;
        *(half4v*)(dst + (size_t)j * 4) = h;
    }
}

// ---------------------------------------------------------------------------
// QKV GEMM: C[m][n] = sum_k A[m][k]*W[n][k] + bias[n], f16 MFMA.
// BM=BN=128, BK=64 (128B LDS rows), 256 threads (4 waves, 2x2 of 64x64).
// LDS XOR-swizzle: logical byte-in-row lb at phys (lb ^ ((row&7)<<4));
// staged with linear global_load_lds dest + inverse-swizzled global source,
// fragment reads apply the same XOR -> 2-way (free) bank pattern.
// M=8704, N=3072, K=1024 all exactly divisible -> no bounds checks.
// ---------------------------------------------------------------------------
__global__ __launch_bounds__(256)
void qkv_gemm_kernel(const _Float16* __restrict__ Ah, const _Float16* __restrict__ Wh,
                     const float* __restrict__ bias,
                     _Float16* __restrict__ Qo, _Float16* __restrict__ Ko,
                     _Float16* __restrict__ Vo,
                     int Kd, int dim)
{
    const int bm = blockIdx.x, bn = blockIdx.y;
    const int t = threadIdx.x;
    const int wid = t >> 6, lane = t & 63;
    const int wr = wid >> 1, wc = wid & 1;
    const int fr = lane & 15, fq = lane >> 4;

    __shared__ _Float16 As[128 * 64];   // 16 KB, swizzled 128B rows
    __shared__ _Float16 Bs[128 * 64];

    const int m0 = bm * 128, n0 = bn * 128;

    f32x4 acc[4][4];
#pragma unroll
    for (int m = 0; m < 4; ++m)
#pragma unroll
        for (int n = 0; n < 4; ++n) acc[m][n] = (f32x4)0.f;

    float biasv[4];
#pragma unroll
    for (int n = 0; n < 4; ++n)
        biasv[n] = bias[n0 + wc * 64 + n * 16 + fr];

    // staging geometry: chunk c in [0,1024): phys byte = c*16,
    // row r = c>>3, slot = (c&7)*16, logical byte lb = slot ^ ((r&7)<<4)
    int srow[4], slb[4];
#pragma unroll
    for (int i = 0; i < 4; ++i) {
        int c = t + 256 * i;
        srow[i] = c >> 3;
        slb[i]  = ((c & 7) << 4) ^ ((srow[i] & 7) << 4);
    }

    for (int k0 = 0; k0 < Kd; k0 += 64) {
        __syncthreads();   // previous iter's LDS reads done
        {
            const char* Ab = (const char*)Ah + ((size_t)m0 * Kd + k0) * 2;
            const char* Bb = (const char*)Wh + ((size_t)n0 * Kd + k0) * 2;
#pragma unroll
            for (int i = 0; i < 4; ++i) {
                int phys = (t + 256 * i) * 16;
                __builtin_amdgcn_global_load_lds(GLP(Ab + (size_t)srow[i] * Kd * 2 + slb[i]),
                                                 LDSP((char*)As + phys), 16, 0, 0);
                __builtin_amdgcn_global_load_lds(GLP(Bb + (size_t)srow[i] * Kd * 2 + slb[i]),
                                                 LDSP((char*)Bs + phys), 16, 0, 0);
            }
        }
        __syncthreads();   // vmcnt drained before barrier by compiler

#pragma unroll
        for (int kc = 0; kc < 2; ++kc) {
            half8 a[4], b[4];
#pragma unroll
            for (int m = 0; m < 4; ++m) {
                int row = wr * 64 + m * 16 + fr;
                a[m] = *(const half8*)((const char*)As + row * 128 +
                        ((kc * 64 + fq * 16) ^ ((fr & 7) << 4)));
            }
#pragma unroll
            for (int n = 0; n < 4; ++n) {
                int row = wc * 64 + n * 16 + fr;
                b[n] = *(const half8*)((const char*)Bs + row * 128 +
                        ((kc * 64 + fq * 16) ^ ((fr & 7) << 4)));
            }
#pragma unroll
            for (int m = 0; m < 4; ++m)
#pragma unroll
                for (int n = 0; n < 4; ++n)
                    acc[m][n] = __builtin_amdgcn_mfma_f32_16x16x32_f16(a[m], b[n], acc[m][n], 0, 0, 0);
        }
    }

    // epilogue: bias, scatter to Q/K/V (f16). BN=128 never straddles Q/K/V.
    const int which = n0 / dim;
    const int offb  = n0 - which * dim;
    _Float16* dst = (which == 0) ? Qo : (which == 1) ? Ko : Vo;
#pragma unroll
    for (int m = 0; m < 4; ++m) {
#pragma unroll
        for (int n = 0; n < 4; ++n) {
            int gc = offb + wc * 64 + n * 16 + fr;
#pragma unroll
            for (int j = 0; j < 4; ++j) {
                int gm = m0 + wr * 64 + m * 16 + fq * 4 + j;
                dst[(size_t)gm * dim + gc] = (_Float16)(acc[m][n][j] + biasv[n]);
            }
        }
    }
}

// ---------------------------------------------------------------------------
// MFMA flash attention (unchanged, validated r8).
// ---------------------------------------------------------------------------
__global__ __launch_bounds__(256)
void attn_kernel(const _Float16* __restrict__ Q, const _Float16* __restrict__ K,
                 const _Float16* __restrict__ V, const int* __restrict__ cu,
                 float* __restrict__ out, int dim, int H, int B)
{
    const int w  = blockIdx.x;
    const int h  = w & (H - 1);
    const int wq = w / H;

    // heavy-first schedule: reversed-b flat scan (uniform scalar loop)
    int b = -1, qt = 0, acc = 0;
    for (int i = B - 1; i >= 0; --i) {
        int Li = cu[i + 1] - cu[i];
        int nq = (Li + 127) >> 7;
        if (wq >= acc && wq < acc + nq) { b = i; qt = wq - acc; }
        acc += nq;
    }
    if (b < 0) return;

    const int s0 = cu[b];
    const int L  = cu[b + 1] - s0;

    const int t    = threadIdx.x;
    const int wid  = t >> 6, lane = t & 63;
    const int fr   = lane & 15, fq = lane >> 4;

    __shared__ _Float16 Ks[64 * 64];      // 8 KB, swizzled 128B rows
    __shared__ _Float16 Vt[64 * 72];      // 9 KB, [d][kv] padded
    __shared__ _Float16 Ps[4][32 * 72];   // 18 KB, per-wave P [q][kv] padded
    __shared__ float    Fs[4][32];        // per-wave fac / final l

    _Float16* Psw = &Ps[wid][0];
    float*    Fsw = &Fs[wid][0];

    // ---- Q fragments in registers; fold scale*log2(e) (exp2 softmax) ----
    const _Float16 qscale = (_Float16)(0.125f * 1.44269504f);
    half8 aq[2][2];
#pragma unroll
    for (int nt = 0; nt < 2; ++nt)
#pragma unroll
        for (int kc = 0; kc < 2; ++kc) {
            int qrow = qt * 128 + wid * 32 + nt * 16 + fr;
            int qr = (qrow < L) ? qrow : 0;
            half8 v = *(const half8*)(Q + (size_t)(s0 + qr) * dim + h * HD + kc * 32 + fq * 8);
#pragma unroll
            for (int i = 0; i < 8; ++i) v[i] = v[i] * qscale;
            aq[nt][kc] = v;
        }

    f32x4 o[2][4];
    float m2[2], l2[2];
#pragma unroll
    for (int qm = 0; qm < 2; ++qm)
#pragma unroll
        for (int n = 0; n < 4; ++n) o[qm][n] = (f32x4)0.f;
    m2[0] = m2[1] = -3.0e38f;
    l2[0] = l2[1] = 0.f;

    const int nkt = (L + 63) >> 6;
    const int vu = t & 31, vdc = t >> 5;   // V staging: kv pair 2u,2u+1; d = vdc*8..+8

    for (int kt = 0; kt < nkt; ++kt) {
        __syncthreads();   // all waves' Ks/Vt reads of prev tile done

        // ---- stage K: linear LDS dest, XOR-swizzled global source ----
#pragma unroll
        for (int cc = 0; cc < 2; ++cc) {
            int c    = wid * 2 + cc;            // chunk 0..7 (1 KB each)
            int phys = c * 1024 + lane * 16;    // linear LDS byte
            int r    = phys >> 7;               // kv row (128B rows)
            int lb   = (phys & 127) ^ ((r & 7) << 4);
            int krow = kt * 64 + r;
            int kr   = (krow < L) ? krow : 0;
            const char* src = (const char*)K + ((size_t)(s0 + kr) * dim + h * HD) * 2 + lb;
            __builtin_amdgcn_global_load_lds(GLP(src), LDSP((char*)Ks + phys), 16, 0, 0);
        }
        // ---- stage V transposed: Vt[d][kv], packed b32 writes ----
        {
            int k0r = kt * 64 + vu * 2;
            int r0 = (k0r     < L) ? k0r     : 0;
            int r1 = (k0r + 1 < L) ? k0r + 1 : 0;
            half8 v0 = *(const half8*)(V + (size_t)(s0 + r0) * dim + h * HD + vdc * 8);
            half8 v1 = *(const half8*)(V + (size_t)(s0 + r1) * dim + h * HD + vdc * 8);
#pragma unroll
            for (int i = 0; i < 8; ++i) {
                union { _Float16 h[2]; unsigned u; } pk;
                pk.h[0] = v0[i]; pk.h[1] = v1[i];
                *(unsigned*)&Vt[(vdc * 8 + i) * 72 + vu * 2] = pk.u;
            }
        }
        __syncthreads();   // staged data visible

        // ---- S^T = mfma(K, Q/8'): 16 MFMA per wave ----
        f32x4 s2[4][2];
#pragma unroll
        for (int mt = 0; mt < 4; ++mt)
#pragma unroll
            for (int nt = 0; nt < 2; ++nt) s2[mt][nt] = (f32x4)0.f;

#pragma unroll
        for (int mt = 0; mt < 4; ++mt)
#pragma unroll
            for (int kc = 0; kc < 2; ++kc) {
                const half8 bk = *(const half8*)((const char*)Ks +
                    ((mt * 16 + fr) << 7) + (((kc << 6) + (fq << 4)) ^ ((fr & 7) << 4)));
                s2[mt][0] = __builtin_amdgcn_mfma_f32_16x16x32_f16(bk, aq[0][kc], s2[mt][0], 0, 0, 0);
                s2[mt][1] = __builtin_amdgcn_mfma_f32_16x16x32_f16(bk, aq[1][kc], s2[mt][1], 0, 0, 0);
            }

        // ---- mask partial tile (kv = mt*16 + fq*4 + j) ----
        int ksz = L - kt * 64;
        if (ksz < 64) {
#pragma unroll
            for (int mt = 0; mt < 4; ++mt)
#pragma unroll
                for (int j = 0; j < 4; ++j)
                    if (mt * 16 + fq * 4 + j >= ksz) {
                        s2[mt][0][j] = -1.0e30f;
                        s2[mt][1][j] = -1.0e30f;
                    }
        }

        // ---- softmax per nt (q = nt*16+fr): in-reg max + 2 shfl; exp2 ----
#pragma unroll
        for (int nt = 0; nt < 2; ++nt) {
            f32x4 mx4 = s2[0][nt];
#pragma unroll
            for (int mt = 1; mt < 4; ++mt) {
#pragma unroll
                for (int j = 0; j < 4; ++j) mx4[j] = fmaxf(mx4[j], s2[mt][nt][j]);
            }
            float mx = fmaxf(fmaxf(mx4[0], mx4[1]), fmaxf(mx4[2], mx4[3]));
            mx = fmaxf(mx, __shfl_xor(mx, 16));
            mx = fmaxf(mx, __shfl_xor(mx, 32));
            float mnew = fmaxf(m2[nt], mx);
            float facn = __builtin_exp2f(m2[nt] - mnew);
            m2[nt] = mnew;

            f32x4 sum4 = (f32x4)0.f;
#pragma unroll
            for (int mt = 0; mt < 4; ++mt) {
                half4v ph;
#pragma unroll
                for (int j = 0; j < 4; ++j) {
                    float p = __builtin_exp2f(s2[mt][nt][j] - mnew);
                    sum4[j] += p;
                    ph[j] = (_Float16)p;
                }
                // P[q = nt*16+fr][kv = mt*16 + fq*4 .. +3]  (8B write)
                *(half4v*)&Psw[(nt * 16 + fr) * 72 + mt * 16 + fq * 4] = ph;
            }
            float ls = (sum4[0] + sum4[1]) + (sum4[2] + sum4[3]);
            ls += __shfl_xor(ls, 16);
            ls += __shfl_xor(ls, 32);
            l2[nt] = l2[nt] * facn + ls;
            if (fq == 0) Fsw[nt * 16 + fr] = facn;
        }

        // ---- o-rescale: fetch fac for o-rows (q = qm*16 + fq*4 + j) ----
#pragma unroll
        for (int qm = 0; qm < 2; ++qm) {
            f32x4 fj = *(const f32x4*)&Fsw[qm * 16 + fq * 4];
#pragma unroll
            for (int n2 = 0; n2 < 4; ++n2)
#pragma unroll
                for (int j = 0; j < 4; ++j) o[qm][n2][j] *= fj[j];
        }

        // ---- O += P V : 16 MFMA per wave (Ps per-wave -> no barrier) ----
#pragma unroll
        for (int kc = 0; kc < 2; ++kc) {
            half8 ap0 = *(const half8*)&Psw[(0 * 16 + fr) * 72 + kc * 32 + fq * 8];
            half8 ap1 = *(const half8*)&Psw[(1 * 16 + fr) * 72 + kc * 32 + fq * 8];
#pragma unroll
            for (int n2 = 0; n2 < 4; ++n2) {
                half8 bv = *(const half8*)&Vt[(n2 * 16 + fr) * 72 + kc * 32 + fq * 8];
                o[0][n2] = __builtin_amdgcn_mfma_f32_16x16x32_f16(ap0, bv, o[0][n2], 0, 0, 0);
                o[1][n2] = __builtin_amdgcn_mfma_f32_16x16x32_f16(ap1, bv, o[1][n2], 0, 0, 0);
            }
        }
    }

    // ---- final l to o-row lanes via Fs, normalize + store ----
    if (fq == 0) { Fsw[fr] = l2[0]; Fsw[16 + fr] = l2[1]; }
#pragma unroll
    for (int qm = 0; qm < 2; ++qm) {
        f32x4 lj = *(const f32x4*)&Fsw[qm * 16 + fq * 4];
#pragma unroll
        for (int j = 0; j < 4; ++j) {
            int qrow = qt * 128 + wid * 32 + qm * 16 + fq * 4 + j;
            if (qrow >= L) continue;
            float inv = 1.0f / lj[j];
#pragma unroll
            for (int n2 = 0; n2 < 4; ++n2)
                out[(size_t)(s0 + qrow) * dim + h * HD + n2 * 16 + fr] = o[qm][n2][j] * inv;
        }
    }
}

// ---------------------------------------------------------------------------
extern "C" void kernel_launch(void* const* d_in, const int* in_sizes, int n_in,
                              void* d_out, int out_size, void* d_ws, size_t ws_size,
                              hipStream_t stream)
{
    const float* hs   = (const float*)d_in[0];
    const float* W    = (const float*)d_in[1];
    const float* bias = (const float*)d_in[2];
    const int*   cu   = (const int*)d_in[3];

    const int dim3x = in_sizes[2];        // 3072
    const int dim   = dim3x / 3;          // 1024
    const int nnz   = in_sizes[0] / dim;  // 8704
    const int B     = in_sizes[3] - 1;    // 16
    const int H     = dim / HD;           // 16
    const size_t nA = (size_t)nnz * dim;
    const size_t nW = (size_t)dim3x * dim;

    _Float16* Ah = (_Float16*)d_ws;
    _Float16* Wh = Ah + nA;
    _Float16* Qh = Wh + nW;
    _Float16* Kh = Qh + nA;
    _Float16* Vh = Kh + nA;

    cvt_kernel<<<1024, 256, 0, stream>>>(hs, W, Ah, Wh, (int)(nA / 4), (int)(nW / 4));

    dim3 g1(nnz / 128, dim3x / 128);
    qkv_gemm_kernel<<<g1, 256, 0, stream>>>(Ah, Wh, bias, Qh, Kh, Vh, dim, dim);

    const int maxWQ = nnz / 128 + B;      // upper bound on total q-tiles
    attn_kernel<<<maxWQ * H, 256, 0, stream>>>(Qh, Kh, Vh, cu, (float*)d_out, dim, H, B);
}